// Round 9
// baseline (326.395 us; speedup 1.0000x reference)
//
#include <hip/hip_runtime.h>
#include <hip/hip_bf16.h>
#include <hip/hip_fp16.h>

#define N_NODES  100000
#define N_EDGES  3200000
#define N_GRAPHS 1000
#define IN_DIM   10
#define HID      20
#define BN_EPS   1e-5f

#define BSH   8                              // 256-node buckets
#define NB    ((N_NODES + 255) / 256)        // 391 buckets
#define CAP   9216                           // per-bucket capacity (mean 8184 + ~11 sigma)
#define FB    256                            // fill blocks
#define FCHUNK ((N_EDGES + FB - 1) / FB)     // 12500 edges/block
#define NBG   ((N_NODES + 31) / 32)          // 3125 gather blocks (32 nodes, 8 subs)

// ---------------------------------------------------------------------------
// Fill into fixed-capacity 256-node buckets. Pass 1 stashes dst in LDS and
// counts; block reserves per-bucket runs (32-edge avg = 128B) via global
// cursor; pass 2 writes runs densely. packed = src | (dst&255)<<24
// ---------------------------------------------------------------------------
__global__ __launch_bounds__(512) void fill_direct(const int* __restrict__ src,
                                                   const int* __restrict__ dst,
                                                   int* __restrict__ bcur,
                                                   unsigned* __restrict__ packed) {
    __shared__ int sdst[FCHUNK];   // 50,000 B
    __shared__ int cnt[NB];
    __shared__ int base[NB];
    int t = threadIdx.x;
    for (int i = t; i < NB; i += 512) cnt[i] = 0;
    __syncthreads();
    int e0 = blockIdx.x * FCHUNK;
    int e1 = min(e0 + FCHUNK, N_EDGES);
    int m = e1 - e0;
    for (int i = t; i < m; i += 512) {
        int d = dst[e0 + i];
        sdst[i] = d;
        atomicAdd(&cnt[d >> BSH], 1);
    }
    __syncthreads();
    for (int i = t; i < NB; i += 512) {
        int c = cnt[i];
        base[i] = c ? atomicAdd(&bcur[i], c) : 0;
        cnt[i] = 0;
    }
    __syncthreads();
    for (int i = t; i < m; i += 512) {
        int d = sdst[i];
        int b = d >> BSH;
        int r = atomicAdd(&cnt[b], 1);
        packed[(size_t)b * CAP + base[b] + r] =
            (unsigned)src[e0 + i] | ((unsigned)(d & 255) << 24);
    }
}

// ---------------------------------------------------------------------------
// Exclusive scan of bucket counts -> compact csr offsets
// ---------------------------------------------------------------------------
__global__ void scan_buckets(const int* __restrict__ bcur, int* __restrict__ off) {
    __shared__ int lds[512];
    int t = threadIdx.x;
    int v = (t < NB) ? bcur[t] : 0;
    int val = v;
    lds[t] = val; __syncthreads();
    for (int o = 1; o < 512; o <<= 1) {
        int a = (t >= o) ? lds[t - o] : 0;
        __syncthreads();
        val += a; lds[t] = val;
        __syncthreads();
    }
    if (t < NB) off[t] = val - v;
    if (t == 0) off[NB] = N_EDGES;
}

// ---------------------------------------------------------------------------
// Per-bucket counting sort by 8-bit local dst -> compact node-exact CSR + rp
// ---------------------------------------------------------------------------
__global__ __launch_bounds__(512) void sort_bucket(const unsigned* __restrict__ packed,
                                                   const int* __restrict__ bcnt,
                                                   const int* __restrict__ off,
                                                   int* __restrict__ csr,
                                                   int* __restrict__ rp) {
    __shared__ unsigned ebuf[CAP];     // 36,864 B
    __shared__ int cnt[256];
    __shared__ int cur[256];
    int b = blockIdx.x, t = threadIdx.x;
    int m = bcnt[b];
    int o = off[b];
    const unsigned* pb = packed + (size_t)b * CAP;
    for (int i = t; i < m; i += 512) ebuf[i] = pb[i];
    if (t < 256) cnt[t] = 0;
    __syncthreads();
    for (int i = t; i < m; i += 512) atomicAdd(&cnt[ebuf[i] >> 24], 1);
    __syncthreads();
    int v = 0, val = 0;
    if (t < 256) { v = cnt[t]; val = v; cur[t] = val; }
    __syncthreads();
    for (int ofs = 1; ofs < 256; ofs <<= 1) {
        int add = (t < 256 && t >= ofs) ? cur[t - ofs] : 0;
        __syncthreads();
        if (t < 256) { val += add; cur[t] = val; }
        __syncthreads();
    }
    if (t < 256) {
        int node = b * 256 + t;
        if (node <= N_NODES) rp[node] = o + (val - v);
        cur[t] = val - v;
    }
    __syncthreads();
    for (int i = t; i < m; i += 512) {
        unsigned p = ebuf[i];
        int l = p >> 24;
        int pos = atomicAdd(&cur[l], 1);
        csr[o + pos] = (int)(p & 0xFFFFFFu);
    }
}

// ---------------------------------------------------------------------------
// Split x [N][10] f32 into xlo [N][8] (32B rows) + xhi [N][2] (8B rows)
// ---------------------------------------------------------------------------
__global__ void split_x(const float* __restrict__ x,
                        float* __restrict__ xlo, float* __restrict__ xhi) {
    int n = blockIdx.x * blockDim.x + threadIdx.x;
    if (n >= N_NODES) return;
    const float2* xp = (const float2*)(x + (size_t)n * 10);
    float2 v0 = xp[0], v1 = xp[1], v2 = xp[2], v3 = xp[3], v4 = xp[4];
    float4* lp = (float4*)(xlo + (size_t)n * 8);
    float4 a; a.x = v0.x; a.y = v0.y; a.z = v1.x; a.w = v1.y;
    float4 b; b.x = v2.x; b.y = v2.y; b.z = v3.x; b.w = v3.y;
    lp[0] = a; lp[1] = b;
    *(float2*)(xhi + (size_t)n * 2) = v4;
}

// ---------------------------------------------------------------------------
// Gather (+fused prev-layer BN+ReLU) + MLP + BN partials.
// DIN==10: f32 split input (xlo/xhi). DIN==20: fp16 split input (hlo/hhi).
// 8 threads/node, 2-row unroll; subs 0-3 compute 5 channels each; fp16 split
// output via LDS repack; partials stat-major [2*HID][NBG].
// ---------------------------------------------------------------------------
template<int DIN, bool BN>
__global__ __launch_bounds__(256) void gather_mlp8(
        const float* __restrict__ flo, const float* __restrict__ fhi,
        const __half* __restrict__ hlo, const __half* __restrict__ hhi,
        const int* __restrict__ rp, const int* __restrict__ csr,
        const float* __restrict__ W,     // [DIN][HID]
        const float* __restrict__ bias,
        const float* __restrict__ ssin,  // [2*HID] prev-layer scale/shift
        __half* __restrict__ olo,        // [N][16] fp16
        __half* __restrict__ ohi,        // [N][4]  fp16
        float* __restrict__ partials)    // [2*HID][NBG]
{
    __shared__ float sW[DIN * HID];
    __shared__ float sb[HID];
    __shared__ float sss[2 * HID];
    __shared__ float red[4][2 * HID];
    __shared__ __half sh[32][24];        // 48B rows (16B aligned), 20 used
    int t = threadIdx.x;
    for (int i = t; i < DIN * HID; i += 256) sW[i] = W[i];
    if (t < HID) sb[t] = bias[t];
    if constexpr (BN) { if (t < 2 * HID) sss[t] = ssin[t]; }
    __syncthreads();

    int node = blockIdx.x * 32 + (t >> 3);
    int sub  = t & 7;
    float u[DIN];
#pragma unroll
    for (int k = 0; k < DIN; k++) u[k] = 0.0f;

    // accumulate one packed half2 word into channel pair q
    auto acch2 = [&](unsigned w, int q) {
        __half2 h2 = *(const __half2*)&w;
        float2 f = __half22float2(h2);
        float v0 = f.x, v1 = f.y;
        if constexpr (BN) {
            v0 = fmaxf(fmaf(v0, sss[2*q+0], sss[HID+2*q+0]), 0.f);
            v1 = fmaxf(fmaf(v1, sss[2*q+1], sss[HID+2*q+1]), 0.f);
        }
        u[2*q] += v0; u[2*q+1] += v1;
    };
    auto accrow20 = [&](uint4 A, uint4 B, uint2 C) {
        acch2(A.x, 0); acch2(A.y, 1); acch2(A.z, 2); acch2(A.w, 3);
        acch2(B.x, 4); acch2(B.y, 5); acch2(B.z, 6); acch2(B.w, 7);
        acch2(C.x, 8); acch2(C.y, 9);
    };

    if (node < N_NODES) {
        int e0 = rp[node], e1 = rp[node + 1];
        if constexpr (DIN == 20) {
            if (sub == 0) {   // self term
                const uint4* l = (const uint4*)(hlo + (size_t)node * 16);
                uint4 A = l[0], B = l[1];
                uint2 C = *(const uint2*)(hhi + (size_t)node * 4);
                accrow20(A, B, C);
            }
            int e = e0 + sub;
            for (; e + 8 < e1; e += 16) {    // 2 rows in flight
                int s0 = csr[e], s1 = csr[e + 8];
                const uint4* l0 = (const uint4*)(hlo + (size_t)s0 * 16);
                const uint4* l1 = (const uint4*)(hlo + (size_t)s1 * 16);
                uint4 A0 = l0[0], B0 = l0[1];
                uint2 C0 = *(const uint2*)(hhi + (size_t)s0 * 4);
                uint4 A1 = l1[0], B1 = l1[1];
                uint2 C1 = *(const uint2*)(hhi + (size_t)s1 * 4);
                accrow20(A0, B0, C0);
                accrow20(A1, B1, C1);
            }
            if (e < e1) {
                int s0 = csr[e];
                const uint4* l0 = (const uint4*)(hlo + (size_t)s0 * 16);
                uint4 A = l0[0], B = l0[1];
                uint2 C = *(const uint2*)(hhi + (size_t)s0 * 4);
                accrow20(A, B, C);
            }
        } else {
            auto accrow10 = [&](float4 A, float4 B, float2 C) {
                u[0] += A.x; u[1] += A.y; u[2] += A.z; u[3] += A.w;
                u[4] += B.x; u[5] += B.y; u[6] += B.z; u[7] += B.w;
                u[8] += C.x; u[9] += C.y;
            };
            if (sub == 0) {   // self term
                const float4* l = (const float4*)(flo + (size_t)node * 8);
                accrow10(l[0], l[1], *(const float2*)(fhi + (size_t)node * 2));
            }
            int e = e0 + sub;
            for (; e + 8 < e1; e += 16) {
                int s0 = csr[e], s1 = csr[e + 8];
                const float4* l0 = (const float4*)(flo + (size_t)s0 * 8);
                const float4* l1 = (const float4*)(flo + (size_t)s1 * 8);
                float4 A0 = l0[0], B0 = l0[1];
                float2 C0 = *(const float2*)(fhi + (size_t)s0 * 2);
                float4 A1 = l1[0], B1 = l1[1];
                float2 C1 = *(const float2*)(fhi + (size_t)s1 * 2);
                accrow10(A0, B0, C0);
                accrow10(A1, B1, C1);
            }
            if (e < e1) {
                int s0 = csr[e];
                const float4* l0 = (const float4*)(flo + (size_t)s0 * 8);
                accrow10(l0[0], l0[1], *(const float2*)(fhi + (size_t)s0 * 2));
            }
        }
    }

    // merge 8 sub-accumulators
#pragma unroll
    for (int k = 0; k < DIN; k++) {
        u[k] += __shfl_xor(u[k], 1);
        u[k] += __shfl_xor(u[k], 2);
        u[k] += __shfl_xor(u[k], 4);
    }

    // MLP: subs 0-3 compute channels [sub*5, sub*5+5)
    const int c0 = (sub & 3) * 5;
    float out[5];
#pragma unroll
    for (int j = 0; j < 5; j++) out[j] = sb[c0 + j];
#pragma unroll
    for (int k = 0; k < DIN; k++) {
        float uk = u[k];
#pragma unroll
        for (int j = 0; j < 5; j++)
            out[j] = fmaf(uk, sW[k * HID + c0 + j], out[j]);
    }
    bool live = (node < N_NODES) && (sub < 4);
    if (live) {
        int nl = t >> 3;
#pragma unroll
        for (int j = 0; j < 5; j++) sh[nl][c0 + j] = __float2half(out[j]);
    }

    // BN partials (from exact f32 values)
    float msk = live ? 1.0f : 0.0f;
    float s1[5], s2[5];
#pragma unroll
    for (int j = 0; j < 5; j++) {
        float o = out[j] * msk;
        s1[j] = o; s2[j] = o * out[j];
    }
    for (int o = 8; o < 64; o <<= 1) {
#pragma unroll
        for (int j = 0; j < 5; j++) {
            s1[j] += __shfl_down(s1[j], o);
            s2[j] += __shfl_down(s2[j], o);
        }
    }
    int lane = t & 63, wave = t >> 6;
    if (lane < 4) {
#pragma unroll
        for (int j = 0; j < 5; j++) {
            red[wave][lane * 5 + j]       = s1[j];
            red[wave][HID + lane * 5 + j] = s2[j];
        }
    }
    __syncthreads();
    // coalesced fp16 split store: 32B (2x16B) + 8B per node
    if (t < 32) {
        int n2 = blockIdx.x * 32 + t;
        if (n2 < N_NODES) {
            const uint4* sp = (const uint4*)&sh[t][0];
            uint4 a0 = sp[0], a1 = sp[1];
            uint2 a2 = *(const uint2*)&sh[t][16];
            uint4* lp = (uint4*)(olo + (size_t)n2 * 16);
            lp[0] = a0; lp[1] = a1;
            *(uint2*)(ohi + (size_t)n2 * 4) = a2;
        }
    }
    if (t < 2 * HID)
        partials[(size_t)t * NBG + blockIdx.x] =
            red[0][t] + red[1][t] + red[2][t] + red[3][t];
}

// ---------------------------------------------------------------------------
// BN prep: 20 blocks, block c reduces stat rows c and c+20 (coalesced), f64
// ---------------------------------------------------------------------------
__global__ __launch_bounds__(256) void bn_prep(const float* __restrict__ partials,
                                               const float* __restrict__ g,
                                               const float* __restrict__ beta,
                                               float* __restrict__ ss) {
    int c = blockIdx.x, t = threadIdx.x;
    double a1 = 0.0, a2 = 0.0;
    for (int i = t; i < NBG; i += 256) {
        a1 += (double)partials[(size_t)c * NBG + i];
        a2 += (double)partials[(size_t)(c + HID) * NBG + i];
    }
    for (int o = 32; o; o >>= 1) {
        a1 += __shfl_down(a1, o);
        a2 += __shfl_down(a2, o);
    }
    __shared__ double r1[4], r2[4];
    int lane = t & 63, wave = t >> 6;
    if (lane == 0) { r1[wave] = a1; r2[wave] = a2; }
    __syncthreads();
    if (t == 0) {
        double su = r1[0] + r1[1] + r1[2] + r1[3];
        double sq = r2[0] + r2[1] + r2[2] + r2[3];
        double mu  = su / (double)N_NODES;
        double var = sq / (double)N_NODES - mu * mu;
        float sc = g[c] * (float)(1.0 / sqrt(var + (double)BN_EPS));
        ss[c]       = sc;
        ss[HID + c] = beta[c] - (float)mu * sc;
    }
}

// ---------------------------------------------------------------------------
// graph_ptr from sorted batch (handles empty graphs)
// ---------------------------------------------------------------------------
__global__ void gptr_kernel(const int* __restrict__ batch, int* __restrict__ gptr) {
    int n = blockIdx.x * blockDim.x + threadIdx.x;
    if (n >= N_NODES) return;
    int g = batch[n];
    int gp = (n == 0) ? -1 : batch[n - 1];
    for (int q = gp + 1; q <= g; q++) gptr[q] = n;
    if (n == N_NODES - 1)
        for (int q = g + 1; q <= N_GRAPHS; q++) gptr[q] = N_NODES;
}

// ---------------------------------------------------------------------------
// Pool (+fused BN3+ReLU, fp16 split input) + FC, block per graph
// ---------------------------------------------------------------------------
__global__ __launch_bounds__(256) void pool_fc(const __half* __restrict__ hlo,
                                               const __half* __restrict__ hhi,
                                               const int* __restrict__ gptr,
                                               const float* __restrict__ ss,
                                               const float* __restrict__ fcW,
                                               const float* __restrict__ fcb,
                                               float* __restrict__ out) {
    __shared__ float red[12][HID];
    __shared__ float sss[2 * HID];
    __shared__ float pl[HID];
    int g = blockIdx.x, t = threadIdx.x;
    if (t < 2 * HID) sss[t] = ss[t];
    __syncthreads();
    int n0 = gptr[g], n1 = gptr[g + 1];
    if (t < 240) {
        int c = t % HID, grp = t / HID;
        float s = 0.0f;
        for (int n = n0 + grp; n < n1; n += 12) {
            float raw = (c < 16) ? __half2float(hlo[(size_t)n * 16 + c])
                                 : __half2float(hhi[(size_t)n * 4 + (c - 16)]);
            float v = fmaf(raw, sss[c], sss[HID + c]);
            s += v > 0.0f ? v : 0.0f;
        }
        red[grp][c] = s;
    }
    __syncthreads();
    if (t < HID) {
        float a = 0.0f;
#pragma unroll
        for (int q = 0; q < 12; q++) a += red[q][t];
        pl[t] = a;
    }
    __syncthreads();
    if (t < 2) {
        float o = fcb[t];
#pragma unroll
        for (int k = 0; k < HID; k++) o = fmaf(pl[k], fcW[k * 2 + t], o);
        out[g * 2 + t] = o;
    }
}

extern "C" void kernel_launch(void* const* d_in, const int* in_sizes, int n_in,
                              void* d_out, int out_size, void* d_ws, size_t ws_size,
                              hipStream_t stream) {
    const float* x     = (const float*)d_in[0];
    const int*   eidx  = (const int*)d_in[1];
    const int*   batch = (const int*)d_in[2];
    const float* W1 = (const float*)d_in[3];
    const float* b1 = (const float*)d_in[4];
    const float* g1 = (const float*)d_in[5];
    const float* be1 = (const float*)d_in[6];
    const float* W2 = (const float*)d_in[7];
    const float* b2 = (const float*)d_in[8];
    const float* g2 = (const float*)d_in[9];
    const float* be2 = (const float*)d_in[10];
    const float* W3 = (const float*)d_in[11];
    const float* b3 = (const float*)d_in[12];
    const float* g3 = (const float*)d_in[13];
    const float* be3 = (const float*)d_in[14];
    const float* fcW = (const float*)d_in[15];
    const float* fcb = (const float*)d_in[16];
    float* out = (float*)d_out;

    const int* src = eidx;
    const int* dst = eidx + N_EDGES;

    // workspace layout (bytes). packed (build-only, 0..14.42 MB) is aliased by
    // hA*/hB* (0..8 MB) and xlo/xhi (8..12 MB): the build (fill/scan/sort)
    // completes before split_x and the gathers write any of them.
    char* ws = (char*)d_ws;
    __half* hAlo   = (__half*)(ws + 0);              // 100000*16*2 = 3,200,000
    __half* hAhi   = (__half*)(ws + 3200000);        // 100000*4*2  =   800,000
    __half* hBlo   = (__half*)(ws + 4000000);        // 3,200,000
    __half* hBhi   = (__half*)(ws + 7200000);        //   800,000
    float*  xlo    = (float*)(ws + 8000000);         // 100000*8*4 = 3,200,000
    float*  xhi    = (float*)(ws + 11200000);        // 100000*2*4 =   800,000
    unsigned* packed = (unsigned*)(ws + 0);          // NB*CAP*4 = 14,415,744 (alias)
    int*   csr     = (int*)(ws + 16000000);          // 12,800,000
    int*   rp      = (int*)(ws + 28800000);          // 400,004
    int*   off     = (int*)(ws + 29200128);          // 1,568
    int*   bcur    = (int*)(ws + 29203328);          // 1,564
    float* partials= (float*)(ws + 29209728);        // 40*3125*4 = 500,000
    float* ss1     = (float*)(ws + 29709728);        // 160
    float* ss2     = (float*)(ws + 29709888);        // 160
    float* ss3     = (float*)(ws + 29710048);        // 160
    int*   gptr    = (int*)(ws + 29710208);          // 4,004

    const int BLK = 256;

    // ---- sorted node-exact CSR (built once, reused by all 3 layers) ----
    hipMemsetAsync(bcur, 0, NB * sizeof(int), stream);
    fill_direct<<<FB, 512, 0, stream>>>(src, dst, bcur, packed);
    scan_buckets<<<1, 512, 0, stream>>>(bcur, off);
    sort_bucket<<<NB, 512, 0, stream>>>(packed, bcur, off, csr, rp);
    gptr_kernel<<<(N_NODES + BLK - 1) / BLK, BLK, 0, stream>>>(batch, gptr);
    split_x<<<(N_NODES + BLK - 1) / BLK, BLK, 0, stream>>>(x, xlo, xhi);

    // ---- layer 1 (DIN=10, f32 split input, no input BN) ----
    gather_mlp8<IN_DIM, false><<<NBG, BLK, 0, stream>>>(xlo, xhi,
        (const __half*)nullptr, (const __half*)nullptr,
        rp, csr, W1, b1, ss1, hAlo, hAhi, partials);
    bn_prep<<<HID, BLK, 0, stream>>>(partials, g1, be1, ss1);

    // ---- layer 2 (DIN=20, fp16 split input, fused BN1+ReLU) ----
    gather_mlp8<HID, true><<<NBG, BLK, 0, stream>>>((const float*)nullptr,
        (const float*)nullptr, hAlo, hAhi,
        rp, csr, W2, b2, ss1, hBlo, hBhi, partials);
    bn_prep<<<HID, BLK, 0, stream>>>(partials, g2, be2, ss2);

    // ---- layer 3 (DIN=20, fp16 split input, fused BN2+ReLU) ----
    gather_mlp8<HID, true><<<NBG, BLK, 0, stream>>>((const float*)nullptr,
        (const float*)nullptr, hBlo, hBhi,
        rp, csr, W3, b3, ss2, hAlo, hAhi, partials);
    bn_prep<<<HID, BLK, 0, stream>>>(partials, g3, be3, ss3);

    // ---- pool (+BN3+ReLU) + FC ----
    pool_fc<<<N_GRAPHS, BLK, 0, stream>>>(hAlo, hAhi, gptr, ss3, fcW, fcb, out);
}